// Round 14
// baseline (194.251 us; speedup 1.0000x reference)
//
#include <hip/hip_runtime.h>
#include <hip/hip_bf16.h>

#define NE 16
#define NN 4
#define DDIM 128
#define KD 64
#define HD 45

typedef _Float16 half8 __attribute__((ext_vector_type(8)));
typedef _Float16 half4 __attribute__((ext_vector_type(4)));
typedef __fp16 half2v __attribute__((ext_vector_type(2)));   // cvt_pkrtz native type
typedef unsigned uint2v __attribute__((ext_vector_type(2)));
typedef float floatx4 __attribute__((ext_vector_type(4)));

// ws byte offsets (static region)
#define OFF_FLAG_B 0
#define OFF_B1_B   64       // fp32 [9][48] (pad cols 45..47 = 0)
#define OFF_XT_B   1792     // fp32 [128]
#define OFF_H0_B   2304     // f16 [2][64]
#define OFF_YW_B   2560     // f16 [4][64]
#define OFF_W1_B   3072     // f16 frag [9][3nt][512]
#define OFF_W2_B   30720    // f16 frag [9][4nt][2kt][512], rows = interleaved h
#define OFF_GW_B   104448   // f16 frag [9][8nt][2kt][512]
#define OFF_HW_B   251904   // f16 frag [4][4nt][4kt][512]
#define OFF_IND_B  317440   // f16 indicator frags [10][64][8] = 10240 B

__device__ __forceinline__ float ldf(const void* p, long i, int f32) {
    if (f32) return ((const float*)p)[i];
    unsigned int u = ((unsigned int)((const unsigned short*)p)[i]) << 16;
    return __uint_as_float(u);
}

// ===== prep2: dtype detect + weight/indicator fragment formatting (1 launch) =====
__global__ void prep2_kernel(const void* w1, const void* b1, const void* w2, const void* h0,
                             const void* hW, const void* gW, const void* Yw, const void* Xt,
                             const void* rs,
                             const int* __restrict__ same_r, const int* __restrict__ anti_r,
                             const int* __restrict__ ne_r, char* wsB) {
    __shared__ int badS;
    if (threadIdx.x == 0) badS = 0;
    __syncthreads();
    {
        const unsigned short* rs16 = (const unsigned short*)rs;
        int bad = 0;
        for (int i = threadIdx.x; i < 2048; i += 256) {
            unsigned int u = ((unsigned int)rs16[i]) << 16;
            float v = __uint_as_float(u);
            if (!(fabsf(v) < 1e6f)) bad = 1;
        }
        if (bad) atomicOr(&badS, 1);
    }
    __syncthreads();
    const int f32 = badS ? 1 : 0;
    if (blockIdx.x == 0 && threadIdx.x == 0) *(int*)(wsB + OFF_FLAG_B) = f32;

    int i = blockIdx.x * 256 + threadIdx.x;
    _Float16* W1F = (_Float16*)(wsB + OFF_W1_B);
    _Float16* W2F = (_Float16*)(wsB + OFF_W2_B);
    _Float16* GWF = (_Float16*)(wsB + OFF_GW_B);
    _Float16* HWF = (_Float16*)(wsB + OFF_HW_B);
    _Float16* INDF= (_Float16*)(wsB + OFF_IND_B);
    float*    B1  = (float*)(wsB + OFF_B1_B);
    float*    XT  = (float*)(wsB + OFF_XT_B);
    _Float16* H0F = (_Float16*)(wsB + OFF_H0_B);
    _Float16* YWF = (_Float16*)(wsB + OFF_YW_B);

    if (i < 13824) {
        int lj = i / 1536, rem = i % 1536;
        int nt = rem >> 9, lane = (rem & 511) >> 3, e = rem & 7;
        int row = ((lane >> 4) << 3) + e;
        int col = (nt << 4) + (lane & 15);
        W1F[i] = (_Float16)((col < 45) ? ldf(w1, lj * 1440 + row * 45 + col, f32) : 0.f);
    }
    if (i < 36864) {
        // W2F rows use the INTERLEAVED hidden slot order: slot q -> h = (q&3)*16 + (q>>2),
        // slot is pad when (q&3)==3 or h>=45  (matches the b64-packed hid store)
        int lj = i / 4096, rem = i & 4095;
        int nt = rem >> 10, kt = (rem >> 9) & 1, lane = (rem & 511) >> 3, e = rem & 7;
        int q = (kt << 5) + ((lane >> 4) << 3) + e;
        int hsel = q & 3, hrow = hsel * 16 + (q >> 2);
        int col = (nt << 4) + (lane & 15);
        W2F[i] = (_Float16)((hsel < 3 && hrow < 45) ? ldf(w2, lj * 2880 + hrow * 64 + col, f32) : 0.f);
    }
    if (i < 73728) {
        int lj = i >> 13, rem = i & 8191;
        int nt = rem >> 10, kt = (rem >> 9) & 1, lane = (rem & 511) >> 3, e = rem & 7;
        int row = (kt << 5) + ((lane >> 4) << 3) + e;
        int col = (nt << 4) + (lane & 15);
        GWF[i] = (_Float16)ldf(gW, lj * 8192 + row * 128 + col, f32);
    }
    if (i < 32768) {
        int lj = i >> 13, rem = i & 8191;
        int nt = rem >> 11, kt = (rem >> 9) & 3, lane = (rem & 511) >> 3, e = rem & 7;
        int row = (kt << 5) + ((lane >> 4) << 3) + e;
        int col = (nt << 4) + (lane & 15);
        HWF[i] = (_Float16)ldf(hW, lj * 8192 + row * 64 + col, f32);
    }
    // indicator fragments [10 frags][64 lanes][8 elems]
    if (i < 5120) {
        int c = i >> 9, rem = i & 511;
        int ln = rem >> 3, ii = rem & 7;
        int cls = (c < 4) ? 0 : ((c < 8) ? 1 : 2);
        int lc  = c - ((cls == 0) ? 0 : ((cls == 1) ? 4 : 8));
        int qd = ln >> 4, lm = ln & 15;
        int e = lc * 32 + qd * 8 + ii;
        int cnt = (cls == 0) ? 112 : ((cls == 1) ? 128 : 64);
        int r = 255;
        if (e < cnt) r = (cls == 0) ? same_r[e] : ((cls == 1) ? anti_r[e] : ne_r[e]);
        INDF[i] = (r == lm) ? (_Float16)1.0f : (_Float16)0.0f;
    }
    if (i < 432) { int lj = i / 48, n = i % 48; B1[i] = (n < 45) ? ldf(b1, lj * 45 + n, f32) : 0.f; }
    if (i < 128) XT[i] = ldf(Xt, i, f32);
    if (i < 128) H0F[i] = (_Float16)ldf(h0, i, f32);
    if (i < 256) YWF[i] = (_Float16)ldf(Yw, i, f32);
}

// ---- distance only for one 16-edge tile (persistent across layers: 1 VGPR) ----
__device__ __forceinline__ float dist_tile(
    const void* __restrict__ rs, const void* __restrict__ coords,
    int b, int lm, int f32, int tloc, int cls,
    const int* __restrict__ S, const int* __restrict__ R)
{
    int le = tloc * 16 + lm;
    int s = S[le], r = R[le];
    long rb = ((long)b * NE + r) * 3;
    float bx = ldf(rs, rb + 0, f32), by = ldf(rs, rb + 1, f32), bz = ldf(rs, rb + 2, f32);
    float ax, ay, az;
    if (cls < 2) {
        long sb = ((long)b * NE + s) * 3;
        ax = ldf(rs, sb + 0, f32); ay = ldf(rs, sb + 1, f32); az = ldf(rs, sb + 2, f32);
    } else {
        ax = ldf(coords, s * 3 + 0, f32); ay = ldf(coords, s * 3 + 1, f32); az = ldf(coords, s * 3 + 2, f32);
    }
    float dx = ax - bx, dy = ay - by, dz = az - bz;
    return sqrtf(dx * dx + dy * dy + dz * dz);
}

// ---- featurize from stored distance (recomputed per layer; fa dies in-phase) ----
__device__ __forceinline__ half8 mkfa8(float d, const float* __restrict__ A0,
                                       const float* __restrict__ B0,
                                       const float* __restrict__ C0)
{
    float d2 = d * d;
    half8 a;
    #pragma unroll
    for (int ii = 0; ii < 8; ++ii) {
        float E = fmaf(A0[ii], d2, fmaf(B0[ii], d, C0[ii]));
        a[ii] = (_Float16)(d2 * __expf(E));
    }
    return a;
}

// ---- one 16-edge tile: MLP -> we, pk-fold hx -> wehT[k][e] ----
// hid: interleaved-hidden layout, b64 stores (slots 4*lm..4*lm+3, 4th = 0),
// XOR swizzle ((row&7)<<4 on byte addr) on both sides.
// hxP: u32-packed hx pairs (k, k+32), row stride 33 u32.
__device__ __forceinline__ void we_tile_weh(
    half8 fa, int lj, int tile,
    const char* __restrict__ wsB, _Float16* __restrict__ hid,
    const unsigned* __restrict__ hxP,
    const unsigned char* __restrict__ sendC,
    _Float16* __restrict__ wehT,               // [64][136] halves
    int lane, int qd, int lm)
{
    const half8* W1F_lj = (const half8*)(wsB + OFF_W1_B) + lj * 192;
    half8 w0 = W1F_lj[lane], w1v = W1F_lj[64 + lane], w2v = W1F_lj[128 + lane];
    const float* B1 = (const float*)(wsB + OFF_B1_B) + lj * 48;
    float bi0 = B1[lm], bi1 = B1[16 + lm], bi2 = B1[32 + lm];
    floatx4 c0 = {bi0, bi0, bi0, bi0};
    floatx4 c1 = {bi1, bi1, bi1, bi1};
    floatx4 c2 = {bi2, bi2, bi2, bi2};
    c0 = __builtin_amdgcn_mfma_f32_16x16x32_f16(fa, w0,  c0, 0, 0, 0);
    c1 = __builtin_amdgcn_mfma_f32_16x16x32_f16(fa, w1v, c1, 0, 0, 0);
    c2 = __builtin_amdgcn_mfma_f32_16x16x32_f16(fa, w2v, c2, 0, 0, 0);
    #pragma unroll
    for (int rr = 0; rr < 4; ++rr) {
        int row = qd * 4 + rr;
        float v0 = c0[rr], v1 = c1[rr], v2 = c2[rr];
        v0 = v0 * __builtin_amdgcn_rcpf(1.f + __expf(-v0));
        v1 = v1 * __builtin_amdgcn_rcpf(1.f + __expf(-v1));
        v2 = v2 * __builtin_amdgcn_rcpf(1.f + __expf(-v2));
        half2v plo = __builtin_amdgcn_cvt_pkrtz(v0, v1);
        half2v phi = __builtin_amdgcn_cvt_pkrtz(v2, 0.f);
        uint2v pk;
        pk[0] = __builtin_bit_cast(unsigned, plo);
        pk[1] = __builtin_bit_cast(unsigned, phi);
        *(uint2v*)((char*)hid + row * 128 + ((lm * 8) ^ ((row & 7) << 4))) = pk;
    }
    int xr = (lm & 7) << 4;
    half8 a0 = *(const half8*)((const char*)hid + lm * 128 + ((qd * 16)      ^ xr));
    half8 a1 = *(const half8*)((const char*)hid + lm * 128 + ((64 + qd * 16) ^ xr));

    unsigned svw = *(const unsigned*)(sendC + tile * 16 + qd * 4);
    int sv0 = svw & 255, sv1 = (svw >> 8) & 255, sv2 = (svw >> 16) & 255, sv3 = svw >> 24;

    const half8* W2F_lj = (const half8*)(wsB + OFF_W2_B) + lj * 512;
    floatx4 acc0 = {0.f,0.f,0.f,0.f}, acc1 = acc0, acc2 = acc0, acc3 = acc0;
    acc0 = __builtin_amdgcn_mfma_f32_16x16x32_f16(a0, W2F_lj[      lane], acc0, 0, 0, 0);
    acc0 = __builtin_amdgcn_mfma_f32_16x16x32_f16(a1, W2F_lj[ 64 + lane], acc0, 0, 0, 0);
    acc1 = __builtin_amdgcn_mfma_f32_16x16x32_f16(a0, W2F_lj[128 + lane], acc1, 0, 0, 0);
    acc1 = __builtin_amdgcn_mfma_f32_16x16x32_f16(a1, W2F_lj[192 + lane], acc1, 0, 0, 0);
    acc2 = __builtin_amdgcn_mfma_f32_16x16x32_f16(a0, W2F_lj[256 + lane], acc2, 0, 0, 0);
    acc2 = __builtin_amdgcn_mfma_f32_16x16x32_f16(a1, W2F_lj[320 + lane], acc2, 0, 0, 0);
    acc3 = __builtin_amdgcn_mfma_f32_16x16x32_f16(a0, W2F_lj[384 + lane], acc3, 0, 0, 0);
    acc3 = __builtin_amdgcn_mfma_f32_16x16x32_f16(a1, W2F_lj[448 + lane], acc3, 0, 0, 0);

    const int eb = tile * 16 + qd * 4;
    #pragma unroll
    for (int p = 0; p < 2; ++p) {
        unsigned ha = hxP[sv0 * 33 + p * 16 + lm];
        unsigned hb = hxP[sv1 * 33 + p * 16 + lm];
        unsigned hc = hxP[sv2 * 33 + p * 16 + lm];
        unsigned hd = hxP[sv3 * 33 + p * 16 + lm];
        floatx4 aL = p ? acc1 : acc0;   // k = p*16+lm
        floatx4 aH = p ? acc3 : acc2;   // k = p*16+lm+32
        half2v m0h = __builtin_amdgcn_cvt_pkrtz(aL[0], aH[0]) * __builtin_bit_cast(half2v, ha);
        half2v m1h = __builtin_amdgcn_cvt_pkrtz(aL[1], aH[1]) * __builtin_bit_cast(half2v, hb);
        half2v m2h = __builtin_amdgcn_cvt_pkrtz(aL[2], aH[2]) * __builtin_bit_cast(half2v, hc);
        half2v m3h = __builtin_amdgcn_cvt_pkrtz(aL[3], aH[3]) * __builtin_bit_cast(half2v, hd);
        unsigned m0 = __builtin_bit_cast(unsigned, m0h);
        unsigned m1 = __builtin_bit_cast(unsigned, m1h);
        unsigned m2 = __builtin_bit_cast(unsigned, m2h);
        unsigned m3 = __builtin_bit_cast(unsigned, m3h);
        uint2v lo, hi;
        lo[0] = (m0 & 0xFFFFu) | (m1 << 16);
        lo[1] = (m2 & 0xFFFFu) | (m3 << 16);
        hi[0] = (m0 >> 16) | (m1 & 0xFFFF0000u);
        hi[1] = (m2 >> 16) | (m3 & 0xFFFF0000u);
        const int klo = p * 16 + lm;
        *(uint2v*)(wehT + klo * 136 + eb) = lo;
        *(uint2v*)(wehT + (klo + 32) * 136 + eb) = hi;
    }
}

// ---- z via indicator MFMA; frags streamed from global (L2-hot) at use ----
__device__ __forceinline__ void z_mfma4(
    const _Float16* __restrict__ wehT, const half8* __restrict__ INDF, int c0,
    _Float16* __restrict__ zh, int wv, int qd, int lm, int lane)
{
    const _Float16* base = wehT + (wv * 16 + lm) * 136 + qd * 8;
    floatx4 zD = {0.f,0.f,0.f,0.f};
    zD = __builtin_amdgcn_mfma_f32_16x16x32_f16(*(const half8*)(base +  0), INDF[(c0 + 0) * 64 + lane], zD, 0, 0, 0);
    zD = __builtin_amdgcn_mfma_f32_16x16x32_f16(*(const half8*)(base + 32), INDF[(c0 + 1) * 64 + lane], zD, 0, 0, 0);
    zD = __builtin_amdgcn_mfma_f32_16x16x32_f16(*(const half8*)(base + 64), INDF[(c0 + 2) * 64 + lane], zD, 0, 0, 0);
    zD = __builtin_amdgcn_mfma_f32_16x16x32_f16(*(const half8*)(base + 96), INDF[(c0 + 3) * 64 + lane], zD, 0, 0, 0);
    half4 h;
    #pragma unroll
    for (int i = 0; i < 4; ++i) h[i] = (_Float16)zD[i];
    *(half4*)(zh + lm * 72 + wv * 16 + qd * 4) = h;
}

__device__ __forceinline__ void z_mfma2(
    const _Float16* __restrict__ wehT, const half8* __restrict__ INDF, int c0,
    _Float16* __restrict__ zh, int wv, int qd, int lm, int lane)
{
    const _Float16* base = wehT + (wv * 16 + lm) * 136 + qd * 8;
    floatx4 zD = {0.f,0.f,0.f,0.f};
    zD = __builtin_amdgcn_mfma_f32_16x16x32_f16(*(const half8*)(base +  0), INDF[(c0 + 0) * 64 + lane], zD, 0, 0, 0);
    zD = __builtin_amdgcn_mfma_f32_16x16x32_f16(*(const half8*)(base + 32), INDF[(c0 + 1) * 64 + lane], zD, 0, 0, 0);
    half4 h;
    #pragma unroll
    for (int i = 0; i < 4; ++i) h[i] = (_Float16)zD[i];
    *(half4*)(zh + lm * 72 + wv * 16 + qd * 4) = h;
}

// ---- eacc += z @ gW for this wave's two output tiles ----
__device__ __forceinline__ void gw_accum(
    int L, int j, int wv, int lane, int qd, int lm,
    const _Float16* __restrict__ zh, const half8* __restrict__ GWF, floatx4 (&eacc)[2])
{
    half8 zf0 = *(const half8*)(zh + lm * 72 + qd * 8);
    half8 zf1 = *(const half8*)(zh + lm * 72 + 32 + qd * 8);
    const half8* G = GWF + (size_t)(L * 3 + j) * 1024;
    #pragma unroll
    for (int u = 0; u < 2; ++u) {
        int t2 = wv * 2 + u;
        eacc[u] = __builtin_amdgcn_mfma_f32_16x16x32_f16(zf0, G[t2 * 128 + lane],      eacc[u], 0, 0, 0);
        eacc[u] = __builtin_amdgcn_mfma_f32_16x16x32_f16(zf1, G[t2 * 128 + 64 + lane], eacc[u], 0, 0, 0);
    }
}

// ================= fully-fused per-b kernel (r12 + d-persistence) ==========
// r13 post-mortem: (256,3) raised occupancy 20->29% but the 5 cross-layer fa
// frags (20 VGPR) no longer fit -> 77MB scratch spill, dur 105->115us.
// Here: persist only the 5 distances d (5 VGPR); recompute fa per layer
// (~500 cy/wave, ~0.6us) so fa + channel constants die within phase A.
// Expect spill-free 84-reg allocation at 3 waves/SIMD.
__global__ __launch_bounds__(256, 3)
void fused_kernel(const void* __restrict__ rs, const void* __restrict__ coords,
                  const int* __restrict__ same_s, const int* __restrict__ same_r,
                  const int* __restrict__ anti_s, const int* __restrict__ anti_r,
                  const int* __restrict__ ne_s,   const int* __restrict__ ne_r,
                  const char* __restrict__ wsB, void* __restrict__ out)
{
    const int b = blockIdx.x;
    const int tid = threadIdx.x;
    const int wv = tid >> 6, lane = tid & 63;
    const int qd = lane >> 4, lm = lane & 15;
    const int f32 = *(const int*)(wsB + OFF_FLAG_B);

    __shared__ __align__(16) _Float16 wehT[64 * 136];   // 17408 B
    __shared__ __align__(16) _Float16 hidA[4][1024];    // 8192 B (interleaved-h layout)
    __shared__ __align__(16) _Float16 zhS[16 * 72];     // 2304 B
    __shared__ unsigned hxPall[2 * 528];                // 4224 B: [j][16 s][33] u32 pairs
    __shared__ unsigned nucP[4 * 33];                   // 528 B
    __shared__ __align__(16) _Float16 elecB[16 * 136];  // 4352 B
    __shared__ unsigned char sendPad[384];
    // total ~37.4 KB

    const _Float16* H0F = (const _Float16*)(wsB + OFF_H0_B);
    const _Float16* YWF = (const _Float16*)(wsB + OFF_YW_B);
    const float*    XT  = (const float*)(wsB + OFF_XT_B);
    const half8*    GWF = (const half8*)(wsB + OFF_GW_B);
    const half8*    HWF = (const half8*)(wsB + OFF_HW_B);
    const half8*    INDF= (const half8*)(wsB + OFF_IND_B);

    for (int i = tid; i < 384; i += 256) {
        int cls = i >> 7, pos = i & 127;
        int cnt = (cls == 0) ? 112 : ((cls == 1) ? 128 : 64);
        int s = 0;
        if (pos < cnt) {
            if (cls == 0)      s = same_s[pos];
            else if (cls == 1) s = anti_s[pos];
            else               s = ne_s[pos];
        }
        sendPad[i] = (unsigned char)s;
    }
    // hxP layer-0: broadcast H0 row to all 16 senders, u32 pair-packed (k, k+32)
    for (int t = tid; t < 1024; t += 256) {
        int j = t >> 9, rem = t & 511, s = rem >> 5, i = rem & 31;
        unsigned lo = ((const unsigned short*)H0F)[j * 64 + i];
        unsigned hi = ((const unsigned short*)H0F)[j * 64 + 32 + i];
        hxPall[j * 528 + s * 33 + i] = lo | (hi << 16);
    }
    if (tid < 128) {
        int s = tid >> 5, i = tid & 31;
        unsigned lo = ((const unsigned short*)YWF)[s * 64 + i];
        unsigned hi = ((const unsigned short*)YWF)[s * 64 + 32 + i];
        nucP[s * 33 + i] = lo | (hi << 16);
    }
    // zero wehT once (class-0 pad cols 112..127 in layer 0; later stale values
    // are finite f16 masked by indicator 0)
    for (int i = tid; i < 4352; i += 256) ((unsigned int*)wehT)[i] = 0u;
    __syncthreads();

    // persistent across layers: 5 distances (5 VGPR)
    float d_s0 = dist_tile(rs, coords, b, lm, f32, wv, 0, same_s, same_r);
    float d_s1 = (wv < 3) ? dist_tile(rs, coords, b, lm, f32, wv + 4, 0, same_s, same_r) : 0.f;
    float d_a0 = dist_tile(rs, coords, b, lm, f32, wv,     1, anti_s, anti_r);
    float d_a1 = dist_tile(rs, coords, b, lm, f32, wv + 4, 1, anti_s, anti_r);
    float d_n  = dist_tile(rs, coords, b, lm, f32, wv,     2, ne_s,   ne_r);

    floatx4 eacc[2];
    #pragma unroll
    for (int u = 0; u < 2; ++u) {
        float xv = XT[(wv * 2 + u) * 16 + lm];
        eacc[u][0] = xv; eacc[u][1] = xv; eacc[u][2] = xv; eacc[u][3] = xv;
    }

    _Float16* hid = hidA[wv];

    for (int L = 0; L < 3; ++L) {
        const int lj0 = L * 3;
        // ---- phase A: recompute fa from d (constants + fa die in this phase) ----
        {
            float A0[8], B0[8], C0[8];
            #pragma unroll
            for (int ii = 0; ii < 8; ++ii) {
                float qf = (float)(qd * 8 + ii) * (1.f / 31.f);
                float mu = 10.f * qf * qf;
                float u = 7.f * __builtin_amdgcn_rcpf(1.f + 10.f * qf);
                float is2 = u * u;
                A0[ii] = -is2;
                B0[ii] = 2.f * mu * is2 - 1.f;
                C0[ii] = -(mu * mu) * is2;
            }
            half8 f_s0 = mkfa8(d_s0, A0, B0, C0);
            half8 f_s1 = mkfa8(d_s1, A0, B0, C0);
            half8 f_a0 = mkfa8(d_a0, A0, B0, C0);
            half8 f_a1 = mkfa8(d_a1, A0, B0, C0);
            half8 f_n  = mkfa8(d_n,  A0, B0, C0);

            // ---- class 0: same-spin (7 tiles) ----
            we_tile_weh(f_s0, lj0, wv, wsB, hid, hxPall, sendPad, wehT, lane, qd, lm);
            if (wv < 3)
            we_tile_weh(f_s1, lj0, wv + 4, wsB, hid, hxPall, sendPad, wehT, lane, qd, lm);
            __syncthreads();
            z_mfma4(wehT, INDF, 0, zhS, wv, qd, lm, lane);
            __syncthreads();
            gw_accum(L, 0, wv, lane, qd, lm, zhS, GWF, eacc);
            // ---- class 1: anti-spin (8 tiles) ----
            we_tile_weh(f_a0, lj0 + 1, wv,     wsB, hid, hxPall + 528, sendPad + 128, wehT, lane, qd, lm);
            we_tile_weh(f_a1, lj0 + 1, wv + 4, wsB, hid, hxPall + 528, sendPad + 128, wehT, lane, qd, lm);
            __syncthreads();
            z_mfma4(wehT, INDF, 4, zhS, wv, qd, lm, lane);
            __syncthreads();
            gw_accum(L, 1, wv, lane, qd, lm, zhS, GWF, eacc);
            // ---- class 2: nuclear (4 tiles) ----
            we_tile_weh(f_n, lj0 + 2, wv, wsB, hid, nucP, sendPad + 256, wehT, lane, qd, lm);
            __syncthreads();
            z_mfma2(wehT, INDF, 8, zhS, wv, qd, lm, lane);
            __syncthreads();
            gw_accum(L, 2, wv, lane, qd, lm, zhS, GWF, eacc);
        }

        if (L < 2) {
            // hx for next layer: elec (f16) -> hW MFMA -> hxPall (u16 halves of pairs)
            #pragma unroll
            for (int u = 0; u < 2; ++u) {
                int t2 = wv * 2 + u;
                #pragma unroll
                for (int r = 0; r < 4; ++r)
                    elecB[(qd * 4 + r) * 136 + t2 * 16 + lm] = (_Float16)eacc[u][r];
            }
            __syncthreads();
            {
                half8 ae0 = *(const half8*)(elecB + lm * 136 +  0 + qd * 8);
                half8 ae1 = *(const half8*)(elecB + lm * 136 + 32 + qd * 8);
                half8 ae2 = *(const half8*)(elecB + lm * 136 + 64 + qd * 8);
                half8 ae3 = *(const half8*)(elecB + lm * 136 + 96 + qd * 8);
                _Float16* hp = (_Float16*)hxPall;
                #pragma unroll
                for (int u = 0; u < 2; ++u) {
                    int idx = wv * 2 + u;
                    int j = idx >> 2, nt = idx & 3;
                    const half8* Bb = HWF + (size_t)(((L * 2 + j) * 4 + nt) * 4) * 64;
                    floatx4 acc = {0.f,0.f,0.f,0.f};
                    acc = __builtin_amdgcn_mfma_f32_16x16x32_f16(ae0, Bb[  0 + lane], acc, 0, 0, 0);
                    acc = __builtin_amdgcn_mfma_f32_16x16x32_f16(ae1, Bb[ 64 + lane], acc, 0, 0, 0);
                    acc = __builtin_amdgcn_mfma_f32_16x16x32_f16(ae2, Bb[128 + lane], acc, 0, 0, 0);
                    acc = __builtin_amdgcn_mfma_f32_16x16x32_f16(ae3, Bb[192 + lane], acc, 0, 0, 0);
                    const int k = nt * 16 + lm;
                    #pragma unroll
                    for (int r = 0; r < 4; ++r) {
                        int s = qd * 4 + r;
                        hp[(j * 528 + s * 33 + (k & 31)) * 2 + (k >> 5)] = (_Float16)acc[r];
                    }
                }
            }
            __syncthreads();   // hxP ready before next layer's we_tile reads
        }
    }

    if (f32) {
        float* o = (float*)out + (size_t)b * 2048;
        #pragma unroll
        for (int u = 0; u < 2; ++u)
            #pragma unroll
            for (int r = 0; r < 4; ++r)
                o[(qd * 4 + r) * 128 + (wv * 2 + u) * 16 + lm] = eacc[u][r];
    } else {
        __hip_bfloat16* o = (__hip_bfloat16*)out + (size_t)b * 2048;
        #pragma unroll
        for (int u = 0; u < 2; ++u)
            #pragma unroll
            for (int r = 0; r < 4; ++r)
                o[(qd * 4 + r) * 128 + (wv * 2 + u) * 16 + lm] = __float2bfloat16(eacc[u][r]);
    }
}

extern "C" void kernel_launch(void* const* d_in, const int* in_sizes, int n_in,
                              void* d_out, int out_size, void* d_ws, size_t ws_size,
                              hipStream_t stream) {
    const void* rs     = d_in[0];
    const void* coords = d_in[1];
    const void* X_tab  = d_in[2];
    const void* Y_w    = d_in[3];
    const void* wW1    = d_in[4];
    const void* wb1    = d_in[5];
    const void* wW2    = d_in[6];
    const void* h0     = d_in[7];
    const void* hW     = d_in[8];
    const void* gW     = d_in[9];
    const int* same_s = (const int*)d_in[10];
    const int* same_r = (const int*)d_in[11];
    const int* anti_s = (const int*)d_in[12];
    const int* anti_r = (const int*)d_in[13];
    const int* ne_s   = (const int*)d_in[14];
    const int* ne_r   = (const int*)d_in[15];
    char* wsB = (char*)d_ws;

    const int Bn = in_sizes[0] / (NE * 3);

    prep2_kernel<<<288, 256, 0, stream>>>(wW1, wb1, wW2, h0, hW, gW, Y_w, X_tab, rs,
                                          same_r, anti_r, ne_r, wsB);
    fused_kernel<<<Bn, 256, 0, stream>>>(rs, coords, same_s, same_r, anti_s, anti_r,
                                         ne_s, ne_r, wsB, d_out);
}

// Round 16
// 182.927 us; speedup vs baseline: 1.0619x; 1.0619x over previous
//
#include <hip/hip_runtime.h>
#include <hip/hip_bf16.h>

#define NE 16
#define NN 4
#define DDIM 128
#define KD 64
#define HD 45

typedef _Float16 half8 __attribute__((ext_vector_type(8)));
typedef _Float16 half4 __attribute__((ext_vector_type(4)));
typedef __fp16 half2v __attribute__((ext_vector_type(2)));   // cvt_pkrtz native type
typedef unsigned uint2v __attribute__((ext_vector_type(2)));
typedef float floatx4 __attribute__((ext_vector_type(4)));

// ws byte offsets (static region)
#define OFF_FLAG_B 0
#define OFF_B1_B   64       // fp32 [9][48] (pad cols 45..47 = 0)
#define OFF_XT_B   1792     // fp32 [128]
#define OFF_H0_B   2304     // f16 [2][64]
#define OFF_YW_B   2560     // f16 [4][64]
#define OFF_W1_B   3072     // f16 frag [9][3nt][512]
#define OFF_W2_B   30720    // f16 frag [9][4nt][2kt][512], rows = interleaved h
#define OFF_GW_B   104448   // f16 frag [9][8nt][2kt][512]
#define OFF_HW_B   251904   // f16 frag [4][4nt][4kt][512]
#define OFF_IND_B  317440   // f16 indicator frags [10][64][8] = 10240 B

__device__ __forceinline__ float ldf(const void* p, long i, int f32) {
    if (f32) return ((const float*)p)[i];
    unsigned int u = ((unsigned int)((const unsigned short*)p)[i]) << 16;
    return __uint_as_float(u);
}

// ===== prep2: dtype detect + weight/indicator fragment formatting (1 launch) =====
__global__ void prep2_kernel(const void* w1, const void* b1, const void* w2, const void* h0,
                             const void* hW, const void* gW, const void* Yw, const void* Xt,
                             const void* rs,
                             const int* __restrict__ same_r, const int* __restrict__ anti_r,
                             const int* __restrict__ ne_r, char* wsB) {
    __shared__ int badS;
    if (threadIdx.x == 0) badS = 0;
    __syncthreads();
    {
        const unsigned short* rs16 = (const unsigned short*)rs;
        int bad = 0;
        for (int i = threadIdx.x; i < 2048; i += 256) {
            unsigned int u = ((unsigned int)rs16[i]) << 16;
            float v = __uint_as_float(u);
            if (!(fabsf(v) < 1e6f)) bad = 1;
        }
        if (bad) atomicOr(&badS, 1);
    }
    __syncthreads();
    const int f32 = badS ? 1 : 0;
    if (blockIdx.x == 0 && threadIdx.x == 0) *(int*)(wsB + OFF_FLAG_B) = f32;

    int i = blockIdx.x * 256 + threadIdx.x;
    _Float16* W1F = (_Float16*)(wsB + OFF_W1_B);
    _Float16* W2F = (_Float16*)(wsB + OFF_W2_B);
    _Float16* GWF = (_Float16*)(wsB + OFF_GW_B);
    _Float16* HWF = (_Float16*)(wsB + OFF_HW_B);
    _Float16* INDF= (_Float16*)(wsB + OFF_IND_B);
    float*    B1  = (float*)(wsB + OFF_B1_B);
    float*    XT  = (float*)(wsB + OFF_XT_B);
    _Float16* H0F = (_Float16*)(wsB + OFF_H0_B);
    _Float16* YWF = (_Float16*)(wsB + OFF_YW_B);

    if (i < 13824) {
        int lj = i / 1536, rem = i % 1536;
        int nt = rem >> 9, lane = (rem & 511) >> 3, e = rem & 7;
        int row = ((lane >> 4) << 3) + e;
        int col = (nt << 4) + (lane & 15);
        W1F[i] = (_Float16)((col < 45) ? ldf(w1, lj * 1440 + row * 45 + col, f32) : 0.f);
    }
    if (i < 36864) {
        // W2F rows use the INTERLEAVED hidden slot order: slot q -> h = (q&3)*16 + (q>>2),
        // slot is pad when (q&3)==3 or h>=45  (matches the b64-packed hid store)
        int lj = i / 4096, rem = i & 4095;
        int nt = rem >> 10, kt = (rem >> 9) & 1, lane = (rem & 511) >> 3, e = rem & 7;
        int q = (kt << 5) + ((lane >> 4) << 3) + e;
        int hsel = q & 3, hrow = hsel * 16 + (q >> 2);
        int col = (nt << 4) + (lane & 15);
        W2F[i] = (_Float16)((hsel < 3 && hrow < 45) ? ldf(w2, lj * 2880 + hrow * 64 + col, f32) : 0.f);
    }
    if (i < 73728) {
        int lj = i >> 13, rem = i & 8191;
        int nt = rem >> 10, kt = (rem >> 9) & 1, lane = (rem & 511) >> 3, e = rem & 7;
        int row = (kt << 5) + ((lane >> 4) << 3) + e;
        int col = (nt << 4) + (lane & 15);
        GWF[i] = (_Float16)ldf(gW, lj * 8192 + row * 128 + col, f32);
    }
    if (i < 32768) {
        int lj = i >> 13, rem = i & 8191;
        int nt = rem >> 11, kt = (rem >> 9) & 3, lane = (rem & 511) >> 3, e = rem & 7;
        int row = (kt << 5) + ((lane >> 4) << 3) + e;
        int col = (nt << 4) + (lane & 15);
        HWF[i] = (_Float16)ldf(hW, lj * 8192 + row * 64 + col, f32);
    }
    // indicator fragments [10 frags][64 lanes][8 elems]
    if (i < 5120) {
        int c = i >> 9, rem = i & 511;
        int ln = rem >> 3, ii = rem & 7;
        int cls = (c < 4) ? 0 : ((c < 8) ? 1 : 2);
        int lc  = c - ((cls == 0) ? 0 : ((cls == 1) ? 4 : 8));
        int qd = ln >> 4, lm = ln & 15;
        int e = lc * 32 + qd * 8 + ii;
        int cnt = (cls == 0) ? 112 : ((cls == 1) ? 128 : 64);
        int r = 255;
        if (e < cnt) r = (cls == 0) ? same_r[e] : ((cls == 1) ? anti_r[e] : ne_r[e]);
        INDF[i] = (r == lm) ? (_Float16)1.0f : (_Float16)0.0f;
    }
    if (i < 432) { int lj = i / 48, n = i % 48; B1[i] = (n < 45) ? ldf(b1, lj * 45 + n, f32) : 0.f; }
    if (i < 128) XT[i] = ldf(Xt, i, f32);
    if (i < 128) H0F[i] = (_Float16)ldf(h0, i, f32);
    if (i < 256) YWF[i] = (_Float16)ldf(Yw, i, f32);
}

// ---- distance only for one 16-edge tile (persistent across layers: 1 VGPR) ----
__device__ __forceinline__ float dist_tile(
    const void* __restrict__ rs, const void* __restrict__ coords,
    int b, int lm, int f32, int tloc, int cls,
    const int* __restrict__ S, const int* __restrict__ R)
{
    int le = tloc * 16 + lm;
    int s = S[le], r = R[le];
    long rb = ((long)b * NE + r) * 3;
    float bx = ldf(rs, rb + 0, f32), by = ldf(rs, rb + 1, f32), bz = ldf(rs, rb + 2, f32);
    float ax, ay, az;
    if (cls < 2) {
        long sb = ((long)b * NE + s) * 3;
        ax = ldf(rs, sb + 0, f32); ay = ldf(rs, sb + 1, f32); az = ldf(rs, sb + 2, f32);
    } else {
        ax = ldf(coords, s * 3 + 0, f32); ay = ldf(coords, s * 3 + 1, f32); az = ldf(coords, s * 3 + 2, f32);
    }
    float dx = ax - bx, dy = ay - by, dz = az - bz;
    return sqrtf(dx * dx + dy * dy + dz * dz);
}

// ---- featurize from stored distance (recomputed per layer; fa dies in-phase) ----
__device__ __forceinline__ half8 mkfa8(float d, const float* __restrict__ A0,
                                       const float* __restrict__ B0,
                                       const float* __restrict__ C0)
{
    float d2 = d * d;
    half8 a;
    #pragma unroll
    for (int ii = 0; ii < 8; ++ii) {
        float E = fmaf(A0[ii], d2, fmaf(B0[ii], d, C0[ii]));
        a[ii] = (_Float16)(d2 * __expf(E));
    }
    return a;
}

// ---- one 16-edge tile: MLP -> we, pk-fold hx -> wehT[k][e] ----
// hid: interleaved-hidden layout, b64 stores, XOR swizzle on both sides.
// hxP: u32-packed hx pairs (k, k+32), row stride 33 u32.
// W2 stage runs as TWO sequential (accL, accH) groups to halve the transient
// register peak (8 in-flight W2 frags + 4 accs -> 4 frags + 2 accs).
__device__ __forceinline__ void we_tile_weh(
    half8 fa, int lj, int tile,
    const char* __restrict__ wsB, _Float16* __restrict__ hid,
    const unsigned* __restrict__ hxP,
    const unsigned char* __restrict__ sendC,
    _Float16* __restrict__ wehT,               // [64][136] halves
    int lane, int qd, int lm)
{
    const half8* W1F_lj = (const half8*)(wsB + OFF_W1_B) + lj * 192;
    half8 w0 = W1F_lj[lane], w1v = W1F_lj[64 + lane], w2v = W1F_lj[128 + lane];
    const float* B1 = (const float*)(wsB + OFF_B1_B) + lj * 48;
    float bi0 = B1[lm], bi1 = B1[16 + lm], bi2 = B1[32 + lm];
    floatx4 c0 = {bi0, bi0, bi0, bi0};
    floatx4 c1 = {bi1, bi1, bi1, bi1};
    floatx4 c2 = {bi2, bi2, bi2, bi2};
    c0 = __builtin_amdgcn_mfma_f32_16x16x32_f16(fa, w0,  c0, 0, 0, 0);
    c1 = __builtin_amdgcn_mfma_f32_16x16x32_f16(fa, w1v, c1, 0, 0, 0);
    c2 = __builtin_amdgcn_mfma_f32_16x16x32_f16(fa, w2v, c2, 0, 0, 0);
    #pragma unroll
    for (int rr = 0; rr < 4; ++rr) {
        int row = qd * 4 + rr;
        float v0 = c0[rr], v1 = c1[rr], v2 = c2[rr];
        v0 = v0 * __builtin_amdgcn_rcpf(1.f + __expf(-v0));
        v1 = v1 * __builtin_amdgcn_rcpf(1.f + __expf(-v1));
        v2 = v2 * __builtin_amdgcn_rcpf(1.f + __expf(-v2));
        half2v plo = __builtin_amdgcn_cvt_pkrtz(v0, v1);
        half2v phi = __builtin_amdgcn_cvt_pkrtz(v2, 0.f);
        uint2v pk;
        pk[0] = __builtin_bit_cast(unsigned, plo);
        pk[1] = __builtin_bit_cast(unsigned, phi);
        *(uint2v*)((char*)hid + row * 128 + ((lm * 8) ^ ((row & 7) << 4))) = pk;
    }
    int xr = (lm & 7) << 4;
    half8 a0 = *(const half8*)((const char*)hid + lm * 128 + ((qd * 16)      ^ xr));
    half8 a1 = *(const half8*)((const char*)hid + lm * 128 + ((64 + qd * 16) ^ xr));

    unsigned svw = *(const unsigned*)(sendC + tile * 16 + qd * 4);
    int sv0 = svw & 255, sv1 = (svw >> 8) & 255, sv2 = (svw >> 16) & 255, sv3 = svw >> 24;

    const half8* W2F_lj = (const half8*)(wsB + OFF_W2_B) + lj * 512;
    const int eb = tile * 16 + qd * 4;
    #pragma unroll
    for (int p = 0; p < 2; ++p) {
        // accL covers k = p*16+lm (nt = p); accH covers k = p*16+32+lm (nt = p+2)
        floatx4 accL = {0.f,0.f,0.f,0.f}, accH = accL;
        accL = __builtin_amdgcn_mfma_f32_16x16x32_f16(a0, W2F_lj[ p      * 128 +      lane], accL, 0, 0, 0);
        accL = __builtin_amdgcn_mfma_f32_16x16x32_f16(a1, W2F_lj[ p      * 128 + 64 + lane], accL, 0, 0, 0);
        accH = __builtin_amdgcn_mfma_f32_16x16x32_f16(a0, W2F_lj[(p + 2) * 128 +      lane], accH, 0, 0, 0);
        accH = __builtin_amdgcn_mfma_f32_16x16x32_f16(a1, W2F_lj[(p + 2) * 128 + 64 + lane], accH, 0, 0, 0);

        unsigned ha = hxP[sv0 * 33 + p * 16 + lm];
        unsigned hb = hxP[sv1 * 33 + p * 16 + lm];
        unsigned hc = hxP[sv2 * 33 + p * 16 + lm];
        unsigned hd = hxP[sv3 * 33 + p * 16 + lm];
        half2v m0h = __builtin_amdgcn_cvt_pkrtz(accL[0], accH[0]) * __builtin_bit_cast(half2v, ha);
        half2v m1h = __builtin_amdgcn_cvt_pkrtz(accL[1], accH[1]) * __builtin_bit_cast(half2v, hb);
        half2v m2h = __builtin_amdgcn_cvt_pkrtz(accL[2], accH[2]) * __builtin_bit_cast(half2v, hc);
        half2v m3h = __builtin_amdgcn_cvt_pkrtz(accL[3], accH[3]) * __builtin_bit_cast(half2v, hd);
        unsigned m0 = __builtin_bit_cast(unsigned, m0h);
        unsigned m1 = __builtin_bit_cast(unsigned, m1h);
        unsigned m2 = __builtin_bit_cast(unsigned, m2h);
        unsigned m3 = __builtin_bit_cast(unsigned, m3h);
        uint2v lo, hi;
        lo[0] = (m0 & 0xFFFFu) | (m1 << 16);
        lo[1] = (m2 & 0xFFFFu) | (m3 << 16);
        hi[0] = (m0 >> 16) | (m1 & 0xFFFF0000u);
        hi[1] = (m2 >> 16) | (m3 & 0xFFFF0000u);
        const int klo = p * 16 + lm;
        *(uint2v*)(wehT + klo * 136 + eb) = lo;
        *(uint2v*)(wehT + (klo + 32) * 136 + eb) = hi;
    }
}

// ---- z via indicator MFMA; frags streamed from global (L2-hot) at use ----
__device__ __forceinline__ void z_mfma4(
    const _Float16* __restrict__ wehT, const half8* __restrict__ INDF, int c0,
    _Float16* __restrict__ zh, int wv, int qd, int lm, int lane)
{
    const _Float16* base = wehT + (wv * 16 + lm) * 136 + qd * 8;
    floatx4 zD = {0.f,0.f,0.f,0.f};
    zD = __builtin_amdgcn_mfma_f32_16x16x32_f16(*(const half8*)(base +  0), INDF[(c0 + 0) * 64 + lane], zD, 0, 0, 0);
    zD = __builtin_amdgcn_mfma_f32_16x16x32_f16(*(const half8*)(base + 32), INDF[(c0 + 1) * 64 + lane], zD, 0, 0, 0);
    zD = __builtin_amdgcn_mfma_f32_16x16x32_f16(*(const half8*)(base + 64), INDF[(c0 + 2) * 64 + lane], zD, 0, 0, 0);
    zD = __builtin_amdgcn_mfma_f32_16x16x32_f16(*(const half8*)(base + 96), INDF[(c0 + 3) * 64 + lane], zD, 0, 0, 0);
    half4 h;
    #pragma unroll
    for (int i = 0; i < 4; ++i) h[i] = (_Float16)zD[i];
    *(half4*)(zh + lm * 72 + wv * 16 + qd * 4) = h;
}

__device__ __forceinline__ void z_mfma2(
    const _Float16* __restrict__ wehT, const half8* __restrict__ INDF, int c0,
    _Float16* __restrict__ zh, int wv, int qd, int lm, int lane)
{
    const _Float16* base = wehT + (wv * 16 + lm) * 136 + qd * 8;
    floatx4 zD = {0.f,0.f,0.f,0.f};
    zD = __builtin_amdgcn_mfma_f32_16x16x32_f16(*(const half8*)(base +  0), INDF[(c0 + 0) * 64 + lane], zD, 0, 0, 0);
    zD = __builtin_amdgcn_mfma_f32_16x16x32_f16(*(const half8*)(base + 32), INDF[(c0 + 1) * 64 + lane], zD, 0, 0, 0);
    half4 h;
    #pragma unroll
    for (int i = 0; i < 4; ++i) h[i] = (_Float16)zD[i];
    *(half4*)(zh + lm * 72 + wv * 16 + qd * 4) = h;
}

// ---- eacc += z @ gW for this wave's two output tiles ----
__device__ __forceinline__ void gw_accum(
    int L, int j, int wv, int lane, int qd, int lm,
    const _Float16* __restrict__ zh, const half8* __restrict__ GWF, floatx4 (&eacc)[2])
{
    half8 zf0 = *(const half8*)(zh + lm * 72 + qd * 8);
    half8 zf1 = *(const half8*)(zh + lm * 72 + 32 + qd * 8);
    const half8* G = GWF + (size_t)(L * 3 + j) * 1024;
    #pragma unroll
    for (int u = 0; u < 2; ++u) {
        int t2 = wv * 2 + u;
        eacc[u] = __builtin_amdgcn_mfma_f32_16x16x32_f16(zf0, G[t2 * 128 + lane],      eacc[u], 0, 0, 0);
        eacc[u] = __builtin_amdgcn_mfma_f32_16x16x32_f16(zf1, G[t2 * 128 + 64 + lane], eacc[u], 0, 0, 0);
    }
}

// ================= fully-fused per-b kernel (r12 + halved we_tile peak) ==========
// r13/r14 post-mortem: the spill at (256,3) was the TRANSIENT peak in we_tile
// (8 W2 frags + 4 accs in flight), not the persistent fa set. Here the W2 stage
// runs as two sequential (accL,accH) groups (-24..30 regs peak) under (256,2)
// (a minimum, never forces scratch). If total regs now fit the 128 tier, HW
// residency rises to 4 waves/SIMD on its own.
__global__ __launch_bounds__(256, 2)
void fused_kernel(const void* __restrict__ rs, const void* __restrict__ coords,
                  const int* __restrict__ same_s, const int* __restrict__ same_r,
                  const int* __restrict__ anti_s, const int* __restrict__ anti_r,
                  const int* __restrict__ ne_s,   const int* __restrict__ ne_r,
                  const char* __restrict__ wsB, void* __restrict__ out)
{
    const int b = blockIdx.x;
    const int tid = threadIdx.x;
    const int wv = tid >> 6, lane = tid & 63;
    const int qd = lane >> 4, lm = lane & 15;
    const int f32 = *(const int*)(wsB + OFF_FLAG_B);

    __shared__ __align__(16) _Float16 wehT[64 * 136];   // 17408 B
    __shared__ __align__(16) _Float16 hidA[4][1024];    // 8192 B (interleaved-h layout)
    __shared__ __align__(16) _Float16 zhS[16 * 72];     // 2304 B
    __shared__ unsigned hxPall[2 * 528];                // 4224 B: [j][16 s][33] u32 pairs
    __shared__ unsigned nucP[4 * 33];                   // 528 B
    __shared__ __align__(16) _Float16 elecB[16 * 136];  // 4352 B
    __shared__ unsigned char sendPad[384];
    // total ~37.4 KB

    const _Float16* H0F = (const _Float16*)(wsB + OFF_H0_B);
    const _Float16* YWF = (const _Float16*)(wsB + OFF_YW_B);
    const float*    XT  = (const float*)(wsB + OFF_XT_B);
    const half8*    GWF = (const half8*)(wsB + OFF_GW_B);
    const half8*    HWF = (const half8*)(wsB + OFF_HW_B);
    const half8*    INDF= (const half8*)(wsB + OFF_IND_B);

    for (int i = tid; i < 384; i += 256) {
        int cls = i >> 7, pos = i & 127;
        int cnt = (cls == 0) ? 112 : ((cls == 1) ? 128 : 64);
        int s = 0;
        if (pos < cnt) {
            if (cls == 0)      s = same_s[pos];
            else if (cls == 1) s = anti_s[pos];
            else               s = ne_s[pos];
        }
        sendPad[i] = (unsigned char)s;
    }
    // hxP layer-0: broadcast H0 row to all 16 senders, u32 pair-packed (k, k+32)
    for (int t = tid; t < 1024; t += 256) {
        int j = t >> 9, rem = t & 511, s = rem >> 5, i = rem & 31;
        unsigned lo = ((const unsigned short*)H0F)[j * 64 + i];
        unsigned hi = ((const unsigned short*)H0F)[j * 64 + 32 + i];
        hxPall[j * 528 + s * 33 + i] = lo | (hi << 16);
    }
    if (tid < 128) {
        int s = tid >> 5, i = tid & 31;
        unsigned lo = ((const unsigned short*)YWF)[s * 64 + i];
        unsigned hi = ((const unsigned short*)YWF)[s * 64 + 32 + i];
        nucP[s * 33 + i] = lo | (hi << 16);
    }
    // zero wehT once (class-0 pad cols 112..127 in layer 0; later stale values
    // are finite f16 masked by indicator 0)
    for (int i = tid; i < 4352; i += 256) ((unsigned int*)wehT)[i] = 0u;
    __syncthreads();

    // persistent across layers: 5 distances (5 VGPR)
    float d_s0 = dist_tile(rs, coords, b, lm, f32, wv, 0, same_s, same_r);
    float d_s1 = (wv < 3) ? dist_tile(rs, coords, b, lm, f32, wv + 4, 0, same_s, same_r) : 0.f;
    float d_a0 = dist_tile(rs, coords, b, lm, f32, wv,     1, anti_s, anti_r);
    float d_a1 = dist_tile(rs, coords, b, lm, f32, wv + 4, 1, anti_s, anti_r);
    float d_n  = dist_tile(rs, coords, b, lm, f32, wv,     2, ne_s,   ne_r);

    floatx4 eacc[2];
    #pragma unroll
    for (int u = 0; u < 2; ++u) {
        float xv = XT[(wv * 2 + u) * 16 + lm];
        eacc[u][0] = xv; eacc[u][1] = xv; eacc[u][2] = xv; eacc[u][3] = xv;
    }

    _Float16* hid = hidA[wv];

    for (int L = 0; L < 3; ++L) {
        const int lj0 = L * 3;
        // ---- phase A: recompute fa from d (constants + fa die in this phase) ----
        {
            float A0[8], B0[8], C0[8];
            #pragma unroll
            for (int ii = 0; ii < 8; ++ii) {
                float qf = (float)(qd * 8 + ii) * (1.f / 31.f);
                float mu = 10.f * qf * qf;
                float u = 7.f * __builtin_amdgcn_rcpf(1.f + 10.f * qf);
                float is2 = u * u;
                A0[ii] = -is2;
                B0[ii] = 2.f * mu * is2 - 1.f;
                C0[ii] = -(mu * mu) * is2;
            }
            half8 f_s0 = mkfa8(d_s0, A0, B0, C0);
            half8 f_s1 = mkfa8(d_s1, A0, B0, C0);
            half8 f_a0 = mkfa8(d_a0, A0, B0, C0);
            half8 f_a1 = mkfa8(d_a1, A0, B0, C0);
            half8 f_n  = mkfa8(d_n,  A0, B0, C0);

            // ---- class 0: same-spin (7 tiles) ----
            we_tile_weh(f_s0, lj0, wv, wsB, hid, hxPall, sendPad, wehT, lane, qd, lm);
            if (wv < 3)
            we_tile_weh(f_s1, lj0, wv + 4, wsB, hid, hxPall, sendPad, wehT, lane, qd, lm);
            __syncthreads();
            z_mfma4(wehT, INDF, 0, zhS, wv, qd, lm, lane);
            __syncthreads();
            gw_accum(L, 0, wv, lane, qd, lm, zhS, GWF, eacc);
            // ---- class 1: anti-spin (8 tiles) ----
            we_tile_weh(f_a0, lj0 + 1, wv,     wsB, hid, hxPall + 528, sendPad + 128, wehT, lane, qd, lm);
            we_tile_weh(f_a1, lj0 + 1, wv + 4, wsB, hid, hxPall + 528, sendPad + 128, wehT, lane, qd, lm);
            __syncthreads();
            z_mfma4(wehT, INDF, 4, zhS, wv, qd, lm, lane);
            __syncthreads();
            gw_accum(L, 1, wv, lane, qd, lm, zhS, GWF, eacc);
            // ---- class 2: nuclear (4 tiles) ----
            we_tile_weh(f_n, lj0 + 2, wv, wsB, hid, nucP, sendPad + 256, wehT, lane, qd, lm);
            __syncthreads();
            z_mfma2(wehT, INDF, 8, zhS, wv, qd, lm, lane);
            __syncthreads();
            gw_accum(L, 2, wv, lane, qd, lm, zhS, GWF, eacc);
        }

        if (L < 2) {
            // hx for next layer: elec (f16) -> hW MFMA -> hxPall (u16 halves of pairs)
            #pragma unroll
            for (int u = 0; u < 2; ++u) {
                int t2 = wv * 2 + u;
                #pragma unroll
                for (int r = 0; r < 4; ++r)
                    elecB[(qd * 4 + r) * 136 + t2 * 16 + lm] = (_Float16)eacc[u][r];
            }
            __syncthreads();
            {
                half8 ae0 = *(const half8*)(elecB + lm * 136 +  0 + qd * 8);
                half8 ae1 = *(const half8*)(elecB + lm * 136 + 32 + qd * 8);
                half8 ae2 = *(const half8*)(elecB + lm * 136 + 64 + qd * 8);
                half8 ae3 = *(const half8*)(elecB + lm * 136 + 96 + qd * 8);
                _Float16* hp = (_Float16*)hxPall;
                #pragma unroll
                for (int u = 0; u < 2; ++u) {
                    int idx = wv * 2 + u;
                    int j = idx >> 2, nt = idx & 3;
                    const half8* Bb = HWF + (size_t)(((L * 2 + j) * 4 + nt) * 4) * 64;
                    floatx4 acc = {0.f,0.f,0.f,0.f};
                    acc = __builtin_amdgcn_mfma_f32_16x16x32_f16(ae0, Bb[  0 + lane], acc, 0, 0, 0);
                    acc = __builtin_amdgcn_mfma_f32_16x16x32_f16(ae1, Bb[ 64 + lane], acc, 0, 0, 0);
                    acc = __builtin_amdgcn_mfma_f32_16x16x32_f16(ae2, Bb[128 + lane], acc, 0, 0, 0);
                    acc = __builtin_amdgcn_mfma_f32_16x16x32_f16(ae3, Bb[192 + lane], acc, 0, 0, 0);
                    const int k = nt * 16 + lm;
                    #pragma unroll
                    for (int r = 0; r < 4; ++r) {
                        int s = qd * 4 + r;
                        hp[(j * 528 + s * 33 + (k & 31)) * 2 + (k >> 5)] = (_Float16)acc[r];
                    }
                }
            }
            __syncthreads();   // hxP ready before next layer's we_tile reads
        }
    }

    if (f32) {
        float* o = (float*)out + (size_t)b * 2048;
        #pragma unroll
        for (int u = 0; u < 2; ++u)
            #pragma unroll
            for (int r = 0; r < 4; ++r)
                o[(qd * 4 + r) * 128 + (wv * 2 + u) * 16 + lm] = eacc[u][r];
    } else {
        __hip_bfloat16* o = (__hip_bfloat16*)out + (size_t)b * 2048;
        #pragma unroll
        for (int u = 0; u < 2; ++u)
            #pragma unroll
            for (int r = 0; r < 4; ++r)
                o[(qd * 4 + r) * 128 + (wv * 2 + u) * 16 + lm] = __float2bfloat16(eacc[u][r]);
    }
}

extern "C" void kernel_launch(void* const* d_in, const int* in_sizes, int n_in,
                              void* d_out, int out_size, void* d_ws, size_t ws_size,
                              hipStream_t stream) {
    const void* rs     = d_in[0];
    const void* coords = d_in[1];
    const void* X_tab  = d_in[2];
    const void* Y_w    = d_in[3];
    const void* wW1    = d_in[4];
    const void* wb1    = d_in[5];
    const void* wW2    = d_in[6];
    const void* h0     = d_in[7];
    const void* hW     = d_in[8];
    const void* gW     = d_in[9];
    const int* same_s = (const int*)d_in[10];
    const int* same_r = (const int*)d_in[11];
    const int* anti_s = (const int*)d_in[12];
    const int* anti_r = (const int*)d_in[13];
    const int* ne_s   = (const int*)d_in[14];
    const int* ne_r   = (const int*)d_in[15];
    char* wsB = (char*)d_ws;

    const int Bn = in_sizes[0] / (NE * 3);

    prep2_kernel<<<288, 256, 0, stream>>>(wW1, wb1, wW2, h0, hW, gW, Y_w, X_tab, rs,
                                          same_r, anti_r, ne_r, wsB);
    fused_kernel<<<Bn, 256, 0, stream>>>(rs, coords, same_s, same_r, anti_s, anti_r,
                                         ne_s, ne_r, wsB, d_out);
}